// Round 1
// baseline (1719.773 us; speedup 1.0000x reference)
//
#include <hip/hip_runtime.h>
#include <math.h>

#define BB 4
#define LL 1024
#define DD 1024
#define HH 16
#define DHH 64
// M rows for token-major GEMMs
#define MROWS (BB * LL)   // 4096

// ---------------------------------------------------------------------------
// NT GEMM: C[i,e] = sum_d X[i,d] * W[e,d] + bias[e]
// M x N x K with 64x64 tile, BK=32, 256 threads, 4x4 acc per thread.
// LDS tiles stored transposed [k][row] (pad 68) so inner loop is float4 reads.
// ---------------------------------------------------------------------------
__global__ __launch_bounds__(256) void gemm_nt(const float* __restrict__ X,
                                               const float* __restrict__ W,
                                               const float* __restrict__ bias,
                                               float* __restrict__ C,
                                               int Kdim, int Ndim) {
    __shared__ __align__(16) float As[32][68];  // As[k][i]
    __shared__ __align__(16) float Bs[32][68];  // Bs[k][e]
    const int t  = threadIdx.x;
    const int tx = t & 15, ty = t >> 4;
    const int row0 = blockIdx.x * 64;
    const int col0 = blockIdx.y * 64;
    float acc[4][4] = {};
    for (int kc = 0; kc < Kdim; kc += 32) {
        // 64 rows x 32 cols = 512 float4 each for X and W
        #pragma unroll
        for (int ii = 0; ii < 2; ++ii) {
            int fid = t + 256 * ii;       // 0..511
            int r   = fid >> 3;           // 0..63
            int c4  = fid & 7;            // 0..7
            float4 v = *(const float4*)&X[(size_t)(row0 + r) * Kdim + kc + c4 * 4];
            As[c4*4+0][r] = v.x; As[c4*4+1][r] = v.y;
            As[c4*4+2][r] = v.z; As[c4*4+3][r] = v.w;
            float4 w = *(const float4*)&W[(size_t)(col0 + r) * Kdim + kc + c4 * 4];
            Bs[c4*4+0][r] = w.x; Bs[c4*4+1][r] = w.y;
            Bs[c4*4+2][r] = w.z; Bs[c4*4+3][r] = w.w;
        }
        __syncthreads();
        #pragma unroll
        for (int k = 0; k < 32; ++k) {
            float4 a4 = *(const float4*)&As[k][ty * 4];
            float4 b4 = *(const float4*)&Bs[k][tx * 4];
            float a[4] = {a4.x, a4.y, a4.z, a4.w};
            float b[4] = {b4.x, b4.y, b4.z, b4.w};
            #pragma unroll
            for (int i = 0; i < 4; ++i)
                #pragma unroll
                for (int j = 0; j < 4; ++j)
                    acc[i][j] += a[i] * b[j];
        }
        __syncthreads();
    }
    #pragma unroll
    for (int i = 0; i < 4; ++i) {
        int r = row0 + ty * 4 + i;
        int c = col0 + tx * 4;
        float4 o = make_float4(acc[i][0] + bias[c + 0], acc[i][1] + bias[c + 1],
                               acc[i][2] + bias[c + 2], acc[i][3] + bias[c + 3]);
        *(float4*)&C[(size_t)r * Ndim + c] = o;
    }
}

// ---------------------------------------------------------------------------
// scores + masks + softmax -> writes A[B,H,L,L] to global.
// One block per (bh, 8-query-row tile). 256 threads (4 waves).
// Q,K stored token-major: Q[(b*L+q)*D + h*64 + d].
// ---------------------------------------------------------------------------
__global__ __launch_bounds__(256) void scores_softmax(const float* __restrict__ Q,
                                                      const float* __restrict__ K,
                                                      const float* __restrict__ bemb,
                                                      float* __restrict__ A) {
    __shared__ __align__(16) float Qs[8][64];
    __shared__ __align__(16) float Ks[64][68];
    __shared__ float Ss[8][LL];   // 32 KB of masked scores
    const int t  = threadIdx.x;
    const int qt = blockIdx.x;    // 0..127
    const int bh = blockIdx.y;    // 0..63
    const int b  = bh >> 4;
    const int h  = bh & 15;
    const int q0 = qt * 8;

    if (t < 128) {  // 8 rows x 16 float4
        int r = t >> 4, c4 = t & 15;
        *(float4*)&Qs[r][c4 * 4] =
            *(const float4*)&Q[(size_t)(b * LL + q0 + r) * DD + h * 64 + c4 * 4];
    }
    __syncthreads();

    for (int kc = 0; kc < 16; ++kc) {
        // load 64 K rows x 64 = 1024 float4
        #pragma unroll
        for (int ii = 0; ii < 4; ++ii) {
            int fid = t + 256 * ii;
            int r = fid >> 4, c4 = fid & 15;
            *(float4*)&Ks[r][c4 * 4] =
                *(const float4*)&K[(size_t)(b * LL + kc * 64 + r) * DD + h * 64 + c4 * 4];
        }
        __syncthreads();
        #pragma unroll
        for (int s = 0; s < 2; ++s) {
            int idx = t + 256 * s;     // 0..511 -> 8 q x 64 k
            int ql = idx >> 6, kl = idx & 63;
            float acc = 0.f;
            #pragma unroll
            for (int d4 = 0; d4 < 16; ++d4) {
                float4 a  = *(const float4*)&Qs[ql][d4 * 4];
                float4 kk = *(const float4*)&Ks[kl][d4 * 4];
                acc += a.x * kk.x + a.y * kk.y + a.z * kk.z + a.w * kk.w;
            }
            int kg = kc * 64 + kl;
            bool pres = bemb[b * LL + kg] > 0.f;
            Ss[ql][kg] = pres ? acc * 0.125f : -INFINITY;
        }
        __syncthreads();
    }

    // softmax: wave w handles rows 2w and 2w+1
    const int wave = t >> 6, lane = t & 63;
    #pragma unroll
    for (int rr = 0; rr < 2; ++rr) {
        int r = wave * 2 + rr;
        int q = q0 + r;
        float vals[16];
        float m = -INFINITY;
        #pragma unroll
        for (int j = 0; j < 16; ++j) {
            vals[j] = Ss[r][lane + 64 * j];
            m = fmaxf(m, vals[j]);
        }
        #pragma unroll
        for (int off = 32; off >= 1; off >>= 1) m = fmaxf(m, __shfl_xor(m, off, 64));
        float ssum = 0.f;
        #pragma unroll
        for (int j = 0; j < 16; ++j) {
            vals[j] = __expf(vals[j] - m);
            ssum += vals[j];
        }
        #pragma unroll
        for (int off = 32; off >= 1; off >>= 1) ssum += __shfl_xor(ssum, off, 64);
        bool qpres = bemb[b * LL + q] > 0.f;
        float f = qpres ? (1.f / ssum) : 0.f;   // absent query row -> exact zeros
        float* outp = &A[((size_t)bh * LL + q) * LL];
        #pragma unroll
        for (int j = 0; j < 16; ++j) outp[lane + 64 * j] = vals[j] * f;
    }
}

// ---------------------------------------------------------------------------
// attn[b,q, h*64+d] = sum_k A[bh,q,k] * V[(b*L+k)*D + h*64 + d]
// One block per (bh, 64-q tile), 256 threads, 4x4 acc, K chunks of 64.
// ---------------------------------------------------------------------------
__global__ __launch_bounds__(256) void av_gemm(const float* __restrict__ A,
                                               const float* __restrict__ V,
                                               float* __restrict__ attn) {
    __shared__ __align__(16) float As[64][68];  // As[k][q]
    __shared__ __align__(16) float Vs[64][68];  // Vs[k][d]
    const int t  = threadIdx.x;
    const int tx = t & 15, ty = t >> 4;
    const int qt = blockIdx.x;   // 0..15
    const int bh = blockIdx.y;   // 0..63
    const int b  = bh >> 4;
    const int h  = bh & 15;
    const int q0 = qt * 64;
    float acc[4][4] = {};
    for (int kc = 0; kc < 16; ++kc) {
        #pragma unroll
        for (int ii = 0; ii < 4; ++ii) {
            int fid = t + 256 * ii;   // 0..1023
            int r = fid >> 4, c4 = fid & 15;
            float4 v = *(const float4*)&A[((size_t)bh * LL + q0 + r) * LL + kc * 64 + c4 * 4];
            As[c4*4+0][r] = v.x; As[c4*4+1][r] = v.y;
            As[c4*4+2][r] = v.z; As[c4*4+3][r] = v.w;
            *(float4*)&Vs[r][c4 * 4] =
                *(const float4*)&V[(size_t)(b * LL + kc * 64 + r) * DD + h * 64 + c4 * 4];
        }
        __syncthreads();
        #pragma unroll
        for (int k = 0; k < 64; ++k) {
            float4 a4 = *(const float4*)&As[k][ty * 4];
            float4 v4 = *(const float4*)&Vs[k][tx * 4];
            float a[4] = {a4.x, a4.y, a4.z, a4.w};
            float v[4] = {v4.x, v4.y, v4.z, v4.w};
            #pragma unroll
            for (int i = 0; i < 4; ++i)
                #pragma unroll
                for (int j = 0; j < 4; ++j)
                    acc[i][j] += a[i] * v[j];
        }
        __syncthreads();
    }
    #pragma unroll
    for (int i = 0; i < 4; ++i) {
        int q = q0 + ty * 4 + i;
        float4 o = make_float4(acc[i][0], acc[i][1], acc[i][2], acc[i][3]);
        *(float4*)&attn[(size_t)(b * LL + q) * DD + h * 64 + tx * 4] = o;
    }
}

// ---------------------------------------------------------------------------
extern "C" void kernel_launch(void* const* d_in, const int* in_sizes, int n_in,
                              void* d_out, int out_size, void* d_ws, size_t ws_size,
                              hipStream_t stream) {
    const float* x    = (const float*)d_in[0];   // [B,L,D]
    const float* bemb = (const float*)d_in[1];   // [B,L]
    const float* Wq   = (const float*)d_in[2];
    const float* Wq_b = (const float*)d_in[3];
    const float* Wk   = (const float*)d_in[4];
    const float* Wk_b = (const float*)d_in[5];
    const float* Wv   = (const float*)d_in[6];
    const float* Wv_b = (const float*)d_in[7];
    const float* Wo   = (const float*)d_in[8];
    const float* Wo_b = (const float*)d_in[9];

    float* out  = (float*)d_out;                       // [B,L,D]
    float* Aout = out + (size_t)BB * LL * DD;          // [B,H,L,L]

    // workspace: Q, K, V token-major [B*L, D]; attn reuses Q's buffer
    float* Qw   = (float*)d_ws;
    float* Kw   = Qw + (size_t)MROWS * DD;
    float* Vw   = Kw + (size_t)MROWS * DD;
    float* attn = Qw;  // Q dead after scores_softmax

    dim3 blk(256);
    dim3 gemmGrid(MROWS / 64, DD / 64);   // 64 x 16

    gemm_nt<<<gemmGrid, blk, 0, stream>>>(x, Wq, Wq_b, Qw, DD, DD);
    gemm_nt<<<gemmGrid, blk, 0, stream>>>(x, Wk, Wk_b, Kw, DD, DD);
    gemm_nt<<<gemmGrid, blk, 0, stream>>>(x, Wv, Wv_b, Vw, DD, DD);

    scores_softmax<<<dim3(LL / 8, BB * HH), blk, 0, stream>>>(Qw, Kw, bemb, Aout);

    av_gemm<<<dim3(LL / 64, BB * HH), blk, 0, stream>>>(Aout, Vw, attn);

    gemm_nt<<<gemmGrid, blk, 0, stream>>>(attn, Wo, Wo_b, out, DD, DD);
}

// Round 2
// 653.513 us; speedup vs baseline: 2.6316x; 2.6316x over previous
//
#include <hip/hip_runtime.h>
#include <math.h>

#define BB 4
#define LL 1024
#define DD 1024
#define HH 16
#define MROWS (BB * LL)   // 4096

typedef __attribute__((ext_vector_type(8))) short short8;     // 8 bf16 = 4 VGPR
typedef __attribute__((ext_vector_type(4))) float f32x4;      // MFMA acc
typedef __attribute__((ext_vector_type(4))) unsigned short us4;

__device__ inline unsigned short f2bf(float f) {
    unsigned int u = __builtin_bit_cast(unsigned int, f);
    u += 0x7fffu + ((u >> 16) & 1u);   // RNE
    return (unsigned short)(u >> 16);
}

// ---------------------------------------------------------------------------
// bf16 MFMA NT GEMM, 128x128 tile, BK=64, 256 threads (4 waves, 2x2 wave grid).
// C[i,e] = sum_k X[i,k] * W[e,k] + bias[e].   M=4096, N=1024, K=1024.
// IN_BF16: 0 = X fp32 (cvt in staging), 1 = X bf16 (u16).
// OUT_MODE: 0 = fp32 [M][1024]; 1 = bf16 [M][1024]; 2 = bf16 transposed per-head
//           Vt[((b*16+h)*64+d)*1024 + l]  (for the V projection).
// ---------------------------------------------------------------------------
template<int IN_BF16, int OUT_MODE>
__global__ __launch_bounds__(256) void gemm128(const void* __restrict__ Xv,
                                               const float* __restrict__ W,
                                               const float* __restrict__ bias,
                                               void* __restrict__ Cv) {
    __shared__ unsigned short Xs[128][72];
    __shared__ unsigned short Ws[128][72];
    const int t = threadIdx.x;
    const int lane = t & 63, quad = lane >> 4, lm = lane & 15;
    const int wave = t >> 6;
    const int mo = (wave & 1) * 64, no = (wave >> 1) * 64;
    const int row0 = blockIdx.x * 128, col0 = blockIdx.y * 128;

    f32x4 acc[4][4] = {};

    for (int kc = 0; kc < 1024; kc += 64) {
        if (IN_BF16) {
            const unsigned short* X = (const unsigned short*)Xv;
            #pragma unroll
            for (int i = 0; i < 4; ++i) {
                int id = t + 256 * i; int r = id >> 3, sg = id & 7;
                *(short8*)&Xs[r][sg * 8] =
                    *(const short8*)&X[(size_t)(row0 + r) * 1024 + kc + sg * 8];
            }
        } else {
            const float* X = (const float*)Xv;
            #pragma unroll
            for (int i = 0; i < 8; ++i) {
                int id = t + 256 * i; int r = id >> 4, sg = id & 15;
                float4 v = *(const float4*)&X[(size_t)(row0 + r) * 1024 + kc + sg * 4];
                us4 p = { f2bf(v.x), f2bf(v.y), f2bf(v.z), f2bf(v.w) };
                *(us4*)&Xs[r][sg * 4] = p;
            }
        }
        #pragma unroll
        for (int i = 0; i < 8; ++i) {
            int id = t + 256 * i; int r = id >> 4, sg = id & 15;
            float4 v = *(const float4*)&W[(size_t)(col0 + r) * 1024 + kc + sg * 4];
            us4 p = { f2bf(v.x), f2bf(v.y), f2bf(v.z), f2bf(v.w) };
            *(us4*)&Ws[r][sg * 4] = p;
        }
        __syncthreads();
        #pragma unroll
        for (int s = 0; s < 2; ++s) {
            short8 af[4], bf[4];
            #pragma unroll
            for (int mi = 0; mi < 4; ++mi)
                af[mi] = *(const short8*)&Xs[mo + mi * 16 + lm][s * 32 + quad * 8];
            #pragma unroll
            for (int nj = 0; nj < 4; ++nj)
                bf[nj] = *(const short8*)&Ws[no + nj * 16 + lm][s * 32 + quad * 8];
            #pragma unroll
            for (int mi = 0; mi < 4; ++mi)
                #pragma unroll
                for (int nj = 0; nj < 4; ++nj)
                    acc[mi][nj] = __builtin_amdgcn_mfma_f32_16x16x32_bf16(
                        af[mi], bf[nj], acc[mi][nj], 0, 0, 0);
        }
        __syncthreads();
    }

    #pragma unroll
    for (int mi = 0; mi < 4; ++mi) {
        #pragma unroll
        for (int nj = 0; nj < 4; ++nj) {
            int gr0 = row0 + mo + mi * 16 + quad * 4;
            int gc  = col0 + no + nj * 16 + lm;
            float bv = bias[gc];
            #pragma unroll
            for (int r = 0; r < 4; ++r) {
                float val = acc[mi][nj][r] + bv;
                int gr = gr0 + r;
                if (OUT_MODE == 0) {
                    ((float*)Cv)[(size_t)gr * 1024 + gc] = val;
                } else if (OUT_MODE == 1) {
                    ((unsigned short*)Cv)[(size_t)gr * 1024 + gc] = f2bf(val);
                } else {
                    int bb = gr >> 10, l = gr & 1023;
                    int hh = gc >> 6,  dd = gc & 63;
                    ((unsigned short*)Cv)[(((size_t)bb * 16 + hh) * 64 + dd) * 1024 + l] = f2bf(val);
                }
            }
        }
    }
}

// ---------------------------------------------------------------------------
// scores: S[bh,q,k] = (Q[q,:].K[k,:]) * 0.125, masked (-1e30 on absent keys).
// 128x128 tile per block, contraction 64 (one LDS stage). Writes fp32 raw
// scores into the A output region (softmax_rows normalizes in place).
// ---------------------------------------------------------------------------
__global__ __launch_bounds__(256) void scores128(const unsigned short* __restrict__ Q,
                                                 const unsigned short* __restrict__ K,
                                                 const float* __restrict__ bemb,
                                                 float* __restrict__ S) {
    __shared__ unsigned short Qs[128][72];
    __shared__ unsigned short Ks[128][72];
    const int t = threadIdx.x;
    const int lane = t & 63, quad = lane >> 4, lm = lane & 15;
    const int wave = t >> 6;
    const int mo = (wave & 1) * 64, no = (wave >> 1) * 64;
    const int q0 = blockIdx.x * 128, k0 = blockIdx.y * 128;
    const int bh = blockIdx.z;
    const int b = bh >> 4, h = bh & 15;

    #pragma unroll
    for (int i = 0; i < 4; ++i) {
        int id = t + 256 * i; int r = id >> 3, sg = id & 7;
        *(short8*)&Qs[r][sg * 8] =
            *(const short8*)&Q[(size_t)(b * LL + q0 + r) * 1024 + h * 64 + sg * 8];
        *(short8*)&Ks[r][sg * 8] =
            *(const short8*)&K[(size_t)(b * LL + k0 + r) * 1024 + h * 64 + sg * 8];
    }
    __syncthreads();

    f32x4 acc[4][4] = {};
    #pragma unroll
    for (int s = 0; s < 2; ++s) {
        short8 af[4], bf[4];
        #pragma unroll
        for (int mi = 0; mi < 4; ++mi)
            af[mi] = *(const short8*)&Qs[mo + mi * 16 + lm][s * 32 + quad * 8];
        #pragma unroll
        for (int nj = 0; nj < 4; ++nj)
            bf[nj] = *(const short8*)&Ks[no + nj * 16 + lm][s * 32 + quad * 8];
        #pragma unroll
        for (int mi = 0; mi < 4; ++mi)
            #pragma unroll
            for (int nj = 0; nj < 4; ++nj)
                acc[mi][nj] = __builtin_amdgcn_mfma_f32_16x16x32_bf16(
                    af[mi], bf[nj], acc[mi][nj], 0, 0, 0);
    }

    #pragma unroll
    for (int nj = 0; nj < 4; ++nj) {
        int gk = k0 + no + nj * 16 + lm;
        bool pres = bemb[b * LL + gk] > 0.f;
        #pragma unroll
        for (int mi = 0; mi < 4; ++mi) {
            int gq0 = q0 + mo + mi * 16 + quad * 4;
            #pragma unroll
            for (int r = 0; r < 4; ++r) {
                float val = pres ? acc[mi][nj][r] * 0.125f : -1e30f;
                S[((size_t)bh * LL + gq0 + r) * LL + gk] = val;
            }
        }
    }
}

// ---------------------------------------------------------------------------
// in-place row softmax over S[65536][1024]; one wave per row.
// absent query rows -> exact zeros (softmax then max(A-1,0) == 0).
// ---------------------------------------------------------------------------
__global__ __launch_bounds__(256) void softmax_rows(float* __restrict__ S,
                                                    const float* __restrict__ bemb) {
    const int t = threadIdx.x, lane = t & 63, wave = t >> 6;
    const size_t row = (size_t)blockIdx.x * 4 + wave;   // bh*1024 + q
    const int q = (int)(row & 1023);
    const int bh = (int)(row >> 10);
    const int b = bh >> 4;
    float4* p = (float4*)(S + row * 1024);

    float4 v[4];
    float m = -INFINITY;
    #pragma unroll
    for (int j = 0; j < 4; ++j) {
        v[j] = p[lane + 64 * j];
        m = fmaxf(m, fmaxf(fmaxf(v[j].x, v[j].y), fmaxf(v[j].z, v[j].w)));
    }
    #pragma unroll
    for (int off = 32; off >= 1; off >>= 1) m = fmaxf(m, __shfl_xor(m, off, 64));

    float sum = 0.f;
    #pragma unroll
    for (int j = 0; j < 4; ++j) {
        v[j].x = __expf(v[j].x - m); v[j].y = __expf(v[j].y - m);
        v[j].z = __expf(v[j].z - m); v[j].w = __expf(v[j].w - m);
        sum += v[j].x + v[j].y + v[j].z + v[j].w;
    }
    #pragma unroll
    for (int off = 32; off >= 1; off >>= 1) sum += __shfl_xor(sum, off, 64);

    bool qp = bemb[b * LL + q] > 0.f;
    float f = (qp && sum > 0.f) ? (1.f / sum) : 0.f;
    #pragma unroll
    for (int j = 0; j < 4; ++j) {
        v[j].x *= f; v[j].y *= f; v[j].z *= f; v[j].w *= f;
        p[lane + 64 * j] = v[j];
    }
}

// ---------------------------------------------------------------------------
// AV: attn[b,q, h*64+d] = sum_k A[bh,q,k] * V[k,d].  A fp32 (cvt in staging),
// Vt bf16 [bh][d][k]. 128q x 64d tile, BK=64, wave = 32q x 64d.
// ---------------------------------------------------------------------------
__global__ __launch_bounds__(256) void av128(const float* __restrict__ S,
                                             const unsigned short* __restrict__ Vt,
                                             unsigned short* __restrict__ attn) {
    __shared__ unsigned short As[128][72];
    __shared__ unsigned short Vs[64][72];
    const int t = threadIdx.x;
    const int lane = t & 63, quad = lane >> 4, lm = lane & 15;
    const int wave = t >> 6;
    const int mo = wave * 32;
    const int q0 = blockIdx.x * 128;
    const int bh = blockIdx.y;
    const int b = bh >> 4, h = bh & 15;

    f32x4 acc[2][4] = {};

    for (int kc = 0; kc < 1024; kc += 64) {
        #pragma unroll
        for (int i = 0; i < 8; ++i) {
            int id = t + 256 * i; int r = id >> 4, sg = id & 15;
            float4 v = *(const float4*)&S[((size_t)bh * LL + q0 + r) * LL + kc + sg * 4];
            us4 pk = { f2bf(v.x), f2bf(v.y), f2bf(v.z), f2bf(v.w) };
            *(us4*)&As[r][sg * 4] = pk;
        }
        #pragma unroll
        for (int i = 0; i < 2; ++i) {
            int id = t + 256 * i; int r = id >> 3, sg = id & 7;
            *(short8*)&Vs[r][sg * 8] =
                *(const short8*)&Vt[((size_t)bh * 64 + r) * 1024 + kc + sg * 8];
        }
        __syncthreads();
        #pragma unroll
        for (int s = 0; s < 2; ++s) {
            short8 af[2], bf[4];
            #pragma unroll
            for (int mi = 0; mi < 2; ++mi)
                af[mi] = *(const short8*)&As[mo + mi * 16 + lm][s * 32 + quad * 8];
            #pragma unroll
            for (int nj = 0; nj < 4; ++nj)
                bf[nj] = *(const short8*)&Vs[nj * 16 + lm][s * 32 + quad * 8];
            #pragma unroll
            for (int mi = 0; mi < 2; ++mi)
                #pragma unroll
                for (int nj = 0; nj < 4; ++nj)
                    acc[mi][nj] = __builtin_amdgcn_mfma_f32_16x16x32_bf16(
                        af[mi], bf[nj], acc[mi][nj], 0, 0, 0);
        }
        __syncthreads();
    }

    #pragma unroll
    for (int mi = 0; mi < 2; ++mi)
        #pragma unroll
        for (int nj = 0; nj < 4; ++nj) {
            int gq0 = q0 + mo + mi * 16 + quad * 4;
            int d   = nj * 16 + lm;
            #pragma unroll
            for (int r = 0; r < 4; ++r)
                attn[((size_t)(b * LL + gq0 + r)) * 1024 + h * 64 + d] =
                    f2bf(acc[mi][nj][r]);
        }
}

// ---------------------------------------------------------------------------
extern "C" void kernel_launch(void* const* d_in, const int* in_sizes, int n_in,
                              void* d_out, int out_size, void* d_ws, size_t ws_size,
                              hipStream_t stream) {
    const float* x    = (const float*)d_in[0];
    const float* bemb = (const float*)d_in[1];
    const float* Wq   = (const float*)d_in[2];
    const float* Wq_b = (const float*)d_in[3];
    const float* Wk   = (const float*)d_in[4];
    const float* Wk_b = (const float*)d_in[5];
    const float* Wv   = (const float*)d_in[6];
    const float* Wv_b = (const float*)d_in[7];
    const float* Wo   = (const float*)d_in[8];
    const float* Wo_b = (const float*)d_in[9];

    float* out  = (float*)d_out;                      // [B,L,D] fp32
    float* Aout = out + (size_t)BB * LL * DD;         // [B,H,L,L] fp32

    unsigned short* Qw = (unsigned short*)d_ws;                 // bf16 [4096][1024]
    unsigned short* Kw = Qw + (size_t)MROWS * DD;               // bf16 [4096][1024]
    unsigned short* Vt = Kw + (size_t)MROWS * DD;               // bf16 [64][64][1024]
    unsigned short* Aw = Vt + (size_t)MROWS * DD;               // bf16 attn [4096][1024]

    dim3 blk(256);
    dim3 pgrid(MROWS / 128, DD / 128);   // 32 x 8

    gemm128<0, 1><<<pgrid, blk, 0, stream>>>(x, Wq, Wq_b, Qw);
    gemm128<0, 1><<<pgrid, blk, 0, stream>>>(x, Wk, Wk_b, Kw);
    gemm128<0, 2><<<pgrid, blk, 0, stream>>>(x, Wv, Wv_b, Vt);

    scores128<<<dim3(8, 8, BB * HH), blk, 0, stream>>>(Qw, Kw, bemb, Aout);
    softmax_rows<<<dim3(BB * HH * LL / 4), blk, 0, stream>>>(Aout, bemb);
    av128<<<dim3(LL / 128, BB * HH), blk, 0, stream>>>(Aout, Vt, Aw);

    gemm128<1, 0><<<pgrid, blk, 0, stream>>>(Aw, Wo, Wo_b, out);
}

// Round 3
// 468.454 us; speedup vs baseline: 3.6712x; 1.3950x over previous
//
#include <hip/hip_runtime.h>
#include <math.h>

#define BB 4
#define LL 1024
#define DD 1024
#define HH 16
#define MROWS 4096

typedef __attribute__((ext_vector_type(8))) short short8;     // 8 bf16 = 4 VGPR
typedef __attribute__((ext_vector_type(4))) float f32x4;      // MFMA acc
typedef __attribute__((ext_vector_type(4))) unsigned short us4;

__device__ inline unsigned short f2bf(float f) {
    unsigned int u = __builtin_bit_cast(unsigned int, f);
    u += 0x7fffu + ((u >> 16) & 1u);   // RNE
    return (unsigned short)(u >> 16);
}

// ---------------------------------------------------------------------------
// fp32 -> bf16 bulk convert (float4 -> us4)
// ---------------------------------------------------------------------------
__global__ __launch_bounds__(256) void cvt_bf16(const float* __restrict__ src,
                                                unsigned short* __restrict__ dst,
                                                int n4) {
    int i = blockIdx.x * 256 + threadIdx.x;
    if (i < n4) {
        float4 v = ((const float4*)src)[i];
        us4 p = { f2bf(v.x), f2bf(v.y), f2bf(v.z), f2bf(v.w) };
        ((us4*)dst)[i] = p;
    }
}

// ---------------------------------------------------------------------------
// bf16 MFMA NT GEMM, 128x128 tile, BK=64, 256 threads (4 waves, 2x2 wave grid)
// C[i,e] = sum_k X[i,k] * W[e,k] + bias[e].  Both X,W bf16.
// OUT_MODE: 0 fp32 [M][1024]; 1 bf16 [M][1024]; 2 bf16 per-head-transposed
//           Vt[((b*16+h)*64+d)*1024 + l].
// ---------------------------------------------------------------------------
template<int OUT_MODE>
__global__ __launch_bounds__(256) void gemm128(const unsigned short* __restrict__ X,
                                               const unsigned short* __restrict__ W,
                                               const float* __restrict__ bias,
                                               void* __restrict__ Cv) {
    __shared__ unsigned short Xs[128][72];
    __shared__ unsigned short Ws[128][72];
    const int t = threadIdx.x;
    const int lane = t & 63, quad = lane >> 4, lm = lane & 15;
    const int wave = t >> 6;
    const int mo = (wave & 1) * 64, no = (wave >> 1) * 64;
    const int row0 = blockIdx.x * 128, col0 = blockIdx.y * 128;

    f32x4 acc[4][4] = {};

    for (int kc = 0; kc < 1024; kc += 64) {
        #pragma unroll
        for (int i = 0; i < 4; ++i) {
            int id = t + 256 * i; int r = id >> 3, sg = id & 7;
            *(short8*)&Xs[r][sg * 8] =
                *(const short8*)&X[(size_t)(row0 + r) * 1024 + kc + sg * 8];
            *(short8*)&Ws[r][sg * 8] =
                *(const short8*)&W[(size_t)(col0 + r) * 1024 + kc + sg * 8];
        }
        __syncthreads();
        #pragma unroll
        for (int s = 0; s < 2; ++s) {
            short8 af[4], bf[4];
            #pragma unroll
            for (int mi = 0; mi < 4; ++mi)
                af[mi] = *(const short8*)&Xs[mo + mi * 16 + lm][s * 32 + quad * 8];
            #pragma unroll
            for (int nj = 0; nj < 4; ++nj)
                bf[nj] = *(const short8*)&Ws[no + nj * 16 + lm][s * 32 + quad * 8];
            #pragma unroll
            for (int mi = 0; mi < 4; ++mi)
                #pragma unroll
                for (int nj = 0; nj < 4; ++nj)
                    acc[mi][nj] = __builtin_amdgcn_mfma_f32_16x16x32_bf16(
                        af[mi], bf[nj], acc[mi][nj], 0, 0, 0);
        }
        __syncthreads();
    }

    #pragma unroll
    for (int mi = 0; mi < 4; ++mi) {
        #pragma unroll
        for (int nj = 0; nj < 4; ++nj) {
            int gr0 = row0 + mo + mi * 16 + quad * 4;
            int gc  = col0 + no + nj * 16 + lm;
            float bv = bias[gc];
            #pragma unroll
            for (int r = 0; r < 4; ++r) {
                float val = acc[mi][nj][r] + bv;
                int gr = gr0 + r;
                if (OUT_MODE == 0) {
                    ((float*)Cv)[(size_t)gr * 1024 + gc] = val;
                } else if (OUT_MODE == 1) {
                    ((unsigned short*)Cv)[(size_t)gr * 1024 + gc] = f2bf(val);
                } else {
                    int bb = gr >> 10, l = gr & 1023;
                    int hh = gc >> 6,  dd = gc & 63;
                    ((unsigned short*)Cv)[(((size_t)bb * 16 + hh) * 64 + dd) * 1024 + l] = f2bf(val);
                }
            }
        }
    }
}

// ---------------------------------------------------------------------------
// Fused masked attention: per (bh, 128-q tile) block, 512 threads (8 waves,
// each wave owns 16 q rows). Two passes over 8 K-chunks of 128:
//  pass 1: QK^T MFMA -> online row max m, denom l (registers only)
//  pass 2: recompute QK^T, p = exp(s-m)/l (q-masked), write A fp32 once,
//          p -> bf16 via per-wave LDS tile (C->A layout), PV MFMA -> attn bf16
// Mask is additive -1e30 (finite: no inf-inf NaN; online rescale wipes any
// all-absent-chunk contributions).
// ---------------------------------------------------------------------------
__global__ __launch_bounds__(512) void attn_fused(const unsigned short* __restrict__ Qw,
                                                  const unsigned short* __restrict__ Kw,
                                                  const unsigned short* __restrict__ Vt,
                                                  const float* __restrict__ bemb,
                                                  float* __restrict__ Aout,
                                                  unsigned short* __restrict__ attn) {
    __shared__ unsigned short Ks[128][72];      // K chunk [token][d]
    __shared__ unsigned short Vs[64][136];      // V^T chunk [d][token]
    __shared__ unsigned short Ps[8][16][132];   // per-wave P tile [qrow][kcol]
    __shared__ float maskadd[1024];
    const int t = threadIdx.x;
    const int lane = t & 63, quad = lane >> 4, lm = lane & 15;
    const int w = t >> 6;                       // wave 0..7
    const int q0 = blockIdx.x * 128;
    const int bh = blockIdx.y;
    const int b = bh >> 4, h = bh & 15;
    const int qrow_frag = q0 + w * 16 + lm;            // A-operand row
    const int qrow_acc0 = q0 + w * 16 + quad * 4;      // C-layout row base

    for (int i = t; i < 1024; i += 512)
        maskadd[i] = (bemb[b * 1024 + i] > 0.f) ? 0.f : -1e30f;

    // Q fragments, resident all kernel
    short8 afq[2];
    #pragma unroll
    for (int s = 0; s < 2; ++s)
        afq[s] = *(const short8*)&Qw[(size_t)(b * 1024 + qrow_frag) * 1024 +
                                     h * 64 + s * 32 + quad * 8];

    float mrun[4], lrun[4];
    #pragma unroll
    for (int r = 0; r < 4; ++r) { mrun[r] = -INFINITY; lrun[r] = 0.f; }

    __syncthreads();   // mask ready

    // ---------------- pass 1: m, l ----------------
    for (int c = 0; c < 8; ++c) {
        __syncthreads();   // previous chunk's Ks reads done
        #pragma unroll
        for (int i = 0; i < 2; ++i) {
            int id = t + 512 * i; int r = id >> 3, sg = id & 7;
            *(short8*)&Ks[r][sg * 8] =
                *(const short8*)&Kw[(size_t)(b * 1024 + c * 128 + r) * 1024 +
                                    h * 64 + sg * 8];
        }
        __syncthreads();

        f32x4 acc[8] = {};
        #pragma unroll
        for (int s = 0; s < 2; ++s)
            #pragma unroll
            for (int nj = 0; nj < 8; ++nj) {
                short8 bfk = *(const short8*)&Ks[nj * 16 + lm][s * 32 + quad * 8];
                acc[nj] = __builtin_amdgcn_mfma_f32_16x16x32_bf16(afq[s], bfk, acc[nj], 0, 0, 0);
            }

        float cmax[4] = { -INFINITY, -INFINITY, -INFINITY, -INFINITY };
        #pragma unroll
        for (int nj = 0; nj < 8; ++nj) {
            float ma = maskadd[c * 128 + nj * 16 + lm];
            #pragma unroll
            for (int r = 0; r < 4; ++r) {
                float sv = acc[nj][r] * 0.125f + ma;
                acc[nj][r] = sv;
                cmax[r] = fmaxf(cmax[r], sv);
            }
        }
        #pragma unroll
        for (int r = 0; r < 4; ++r) {
            #pragma unroll
            for (int off = 8; off >= 1; off >>= 1)
                cmax[r] = fmaxf(cmax[r], __shfl_xor(cmax[r], off, 64));
            float mnew = fmaxf(mrun[r], cmax[r]);
            float csum = 0.f;
            #pragma unroll
            for (int nj = 0; nj < 8; ++nj)
                csum += __expf(acc[nj][r] - mnew);
            #pragma unroll
            for (int off = 8; off >= 1; off >>= 1)
                csum += __shfl_xor(csum, off, 64);
            lrun[r] = lrun[r] * __expf(mrun[r] - mnew) + csum;
            mrun[r] = mnew;
        }
    }

    // normalization factor incl. post-softmax query-row mask
    float fnorm[4];
    #pragma unroll
    for (int r = 0; r < 4; ++r) {
        bool qp = bemb[b * 1024 + qrow_acc0 + r] > 0.f;
        fnorm[r] = (qp && lrun[r] > 0.f) ? (1.f / lrun[r]) : 0.f;
    }

    // ---------------- pass 2: write A, PV ----------------
    f32x4 oacc[4] = {};
    for (int c = 0; c < 8; ++c) {
        __syncthreads();
        #pragma unroll
        for (int i = 0; i < 2; ++i) {
            int id = t + 512 * i;
            { int r = id >> 3, sg = id & 7;
              *(short8*)&Ks[r][sg * 8] =
                  *(const short8*)&Kw[(size_t)(b * 1024 + c * 128 + r) * 1024 +
                                      h * 64 + sg * 8]; }
            { int r = id >> 4, sg = id & 15;
              *(short8*)&Vs[r][sg * 8] =
                  *(const short8*)&Vt[((size_t)bh * 64 + r) * 1024 + c * 128 + sg * 8]; }
        }
        __syncthreads();

        f32x4 acc[8] = {};
        #pragma unroll
        for (int s = 0; s < 2; ++s)
            #pragma unroll
            for (int nj = 0; nj < 8; ++nj) {
                short8 bfk = *(const short8*)&Ks[nj * 16 + lm][s * 32 + quad * 8];
                acc[nj] = __builtin_amdgcn_mfma_f32_16x16x32_bf16(afq[s], bfk, acc[nj], 0, 0, 0);
            }

        #pragma unroll
        for (int nj = 0; nj < 8; ++nj) {
            float ma = maskadd[c * 128 + nj * 16 + lm];
            #pragma unroll
            for (int r = 0; r < 4; ++r) {
                float sv = acc[nj][r] * 0.125f + ma;
                float p  = __expf(sv - mrun[r]);
                float a  = p * fnorm[r];
                Aout[((size_t)bh * 1024 + qrow_acc0 + r) * 1024 + c * 128 + nj * 16 + lm] = a;
                Ps[w][quad * 4 + r][nj * 16 + lm] = f2bf(a);
            }
        }

        // PV: A-frag rows = lm (wave-local LDS round-trip; in-wave lgkmcnt
        // ordering makes the cross-lane write->read safe without a barrier)
        #pragma unroll
        for (int ks = 0; ks < 4; ++ks) {
            short8 afp = *(const short8*)&Ps[w][lm][ks * 32 + quad * 8];
            #pragma unroll
            for (int nd = 0; nd < 4; ++nd) {
                short8 bfv = *(const short8*)&Vs[nd * 16 + lm][ks * 32 + quad * 8];
                oacc[nd] = __builtin_amdgcn_mfma_f32_16x16x32_bf16(afp, bfv, oacc[nd], 0, 0, 0);
            }
        }
    }

    #pragma unroll
    for (int nd = 0; nd < 4; ++nd)
        #pragma unroll
        for (int r = 0; r < 4; ++r)
            attn[(size_t)(b * 1024 + qrow_acc0 + r) * 1024 + h * 64 + nd * 16 + lm] =
                f2bf(oacc[nd][r]);
}

// ---------------------------------------------------------------------------
extern "C" void kernel_launch(void* const* d_in, const int* in_sizes, int n_in,
                              void* d_out, int out_size, void* d_ws, size_t ws_size,
                              hipStream_t stream) {
    const float* x    = (const float*)d_in[0];
    const float* bemb = (const float*)d_in[1];
    const float* Wq   = (const float*)d_in[2];
    const float* Wq_b = (const float*)d_in[3];
    const float* Wk   = (const float*)d_in[4];
    const float* Wk_b = (const float*)d_in[5];
    const float* Wv   = (const float*)d_in[6];
    const float* Wv_b = (const float*)d_in[7];
    const float* Wo   = (const float*)d_in[8];
    const float* Wo_b = (const float*)d_in[9];

    float* out  = (float*)d_out;                      // [B,L,D] fp32
    float* Aout = out + (size_t)BB * LL * DD;         // [B,H,L,L] fp32

    // ws layout (u16): x_bf 4M (reused as attn-bf16 later) | 4 weights 1M each
    //                  | Qw 4M | Kw 4M | Vt 4M   = 41.9 MB
    unsigned short* x_bf  = (unsigned short*)d_ws;
    unsigned short* Wq_bf = x_bf  + (size_t)MROWS * DD;
    unsigned short* Wk_bf = Wq_bf + (size_t)DD * DD;
    unsigned short* Wv_bf = Wk_bf + (size_t)DD * DD;
    unsigned short* Wo_bf = Wv_bf + (size_t)DD * DD;
    unsigned short* Qw    = Wo_bf + (size_t)DD * DD;
    unsigned short* Kw    = Qw + (size_t)MROWS * DD;
    unsigned short* Vt    = Kw + (size_t)MROWS * DD;
    unsigned short* Aw    = x_bf;   // x_bf dead after V projection

    dim3 blk(256);
    const int n4x = MROWS * DD / 4;    // 1,048,576
    const int n4w = DD * DD / 4;       // 262,144
    cvt_bf16<<<dim3(n4x / 256), blk, 0, stream>>>(x,  x_bf,  n4x);
    cvt_bf16<<<dim3(n4w / 256), blk, 0, stream>>>(Wq, Wq_bf, n4w);
    cvt_bf16<<<dim3(n4w / 256), blk, 0, stream>>>(Wk, Wk_bf, n4w);
    cvt_bf16<<<dim3(n4w / 256), blk, 0, stream>>>(Wv, Wv_bf, n4w);
    cvt_bf16<<<dim3(n4w / 256), blk, 0, stream>>>(Wo, Wo_bf, n4w);

    dim3 pgrid(MROWS / 128, DD / 128);   // 32 x 8
    gemm128<1><<<pgrid, blk, 0, stream>>>(x_bf, Wq_bf, Wq_b, Qw);
    gemm128<1><<<pgrid, blk, 0, stream>>>(x_bf, Wk_bf, Wk_b, Kw);
    gemm128<2><<<pgrid, blk, 0, stream>>>(x_bf, Wv_bf, Wv_b, Vt);

    attn_fused<<<dim3(LL / 128, BB * HH), dim3(512), 0, stream>>>(
        Qw, Kw, Vt, bemb, Aout, Aw);

    gemm128<0><<<pgrid, blk, 0, stream>>>(Aw, Wo_bf, Wo_b, out);
}

// Round 4
// 441.958 us; speedup vs baseline: 3.8913x; 1.0600x over previous
//
#include <hip/hip_runtime.h>
#include <math.h>

#define BB 4
#define LL 1024
#define DD 1024
#define HH 16
#define MROWS 4096

typedef __attribute__((ext_vector_type(8))) short short8;     // 8 bf16 = 4 VGPR
typedef __attribute__((ext_vector_type(4))) float f32x4;      // MFMA acc
typedef __attribute__((ext_vector_type(4))) unsigned short us4;

__device__ inline unsigned short f2bf(float f) {
    unsigned int u = __builtin_bit_cast(unsigned int, f);
    u += 0x7fffu + ((u >> 16) & 1u);   // RNE
    return (unsigned short)(u >> 16);
}

// async global->LDS, 16B per lane; LDS dest = wave-uniform base + lane*16
__device__ inline void gl2lds16(const void* g, void* l) {
    __builtin_amdgcn_global_load_lds(
        (const __attribute__((address_space(1))) void*)g,
        (__attribute__((address_space(3))) void*)l, 16, 0, 0);
}

// ---------------------------------------------------------------------------
// fused fp32 -> bf16 convert of x (4M) + 4 weights (1M each), float4 units
// ---------------------------------------------------------------------------
__global__ __launch_bounds__(256) void cvt_all(const float* __restrict__ x,
                                               const float* __restrict__ wq,
                                               const float* __restrict__ wk,
                                               const float* __restrict__ wv,
                                               const float* __restrict__ wo,
                                               unsigned short* __restrict__ xb,
                                               unsigned short* __restrict__ wqb,
                                               unsigned short* __restrict__ wkb,
                                               unsigned short* __restrict__ wvb,
                                               unsigned short* __restrict__ wob) {
    int i = blockIdx.x * 256 + threadIdx.x;   // 0 .. 2097151
    const float* src; unsigned short* dst; int k;
    if (i < 1048576) { src = x; dst = xb; k = i; }
    else {
        int j = i - 1048576; int w = j >> 18; k = j & 262143;
        src = (w == 0) ? wq : (w == 1) ? wk : (w == 2) ? wv : wo;
        dst = (w == 0) ? wqb : (w == 1) ? wkb : (w == 2) ? wvb : wob;
    }
    float4 v = ((const float4*)src)[k];
    us4 p = { f2bf(v.x), f2bf(v.y), f2bf(v.z), f2bf(v.w) };
    ((us4*)dst)[k] = p;
}

// ---------------------------------------------------------------------------
// bf16 MFMA NT GEMM core, 128x128 tile, BK=64, 256 threads (2x2 waves).
// global_load_lds staging into unpadded 16KB tiles; XOR swizzle: 16B group g
// of row r stored at column-group g ^ (r & 7)  (rows are 128B = 8 groups).
// Fragment ds_read_b128: banks = 8 distinct 4-bank groups x 2 lanes -> free.
// out_mode: 0 fp32 [M][1024]; 1 bf16 [M][1024]; 2 bf16 per-head transposed
//           Vt[((b*16+h)*64+d)*1024 + l].
// ---------------------------------------------------------------------------
__device__ __forceinline__ void gemm_core(const unsigned short* __restrict__ X,
                                          const unsigned short* __restrict__ W,
                                          const float* __restrict__ bias,
                                          void* __restrict__ Cv, int out_mode) {
    __shared__ unsigned short Xs[128][64];
    __shared__ unsigned short Ws[128][64];
    const int t = threadIdx.x;
    const int lane = t & 63, quad = lane >> 4, lm = lane & 15;
    const int wave = t >> 6;
    const int mo = (wave & 1) * 64, no = (wave >> 1) * 64;
    const int row0 = blockIdx.x * 128, col0 = blockIdx.y * 128;
    const int sw = lm & 7;

    // staging: per wave 4 instrs x (8 rows x 64 bf16 = 1KB); lane -> row wave*32+j*8+(lane>>3),
    // col-group (lane&7); source col-group swizzled by row&7 = lane>>3
    const int r_in = lane >> 3;
    const int sg = (lane & 7) ^ r_in;
    const int lrow = wave * 32 + r_in;
    const unsigned short* xp = X + (size_t)(row0 + lrow) * 1024 + sg * 8;
    const unsigned short* wp = W + (size_t)(col0 + lrow) * 1024 + sg * 8;
    unsigned short* ldsX = &Xs[wave * 32][0];
    unsigned short* ldsW = &Ws[wave * 32][0];

    f32x4 acc[4][4] = {};

    for (int kc = 0; kc < 1024; kc += 64) {
        #pragma unroll
        for (int j = 0; j < 4; ++j) {
            gl2lds16(xp + (size_t)j * 8192 + kc, ldsX + j * 512);
            gl2lds16(wp + (size_t)j * 8192 + kc, ldsW + j * 512);
        }
        __syncthreads();   // drain DMA
        #pragma unroll
        for (int s = 0; s < 2; ++s) {
            short8 af[4], bf[4];
            #pragma unroll
            for (int mi = 0; mi < 4; ++mi)
                af[mi] = *(const short8*)&Xs[mo + mi * 16 + lm][((s * 4 + quad) ^ sw) * 8];
            #pragma unroll
            for (int nj = 0; nj < 4; ++nj)
                bf[nj] = *(const short8*)&Ws[no + nj * 16 + lm][((s * 4 + quad) ^ sw) * 8];
            #pragma unroll
            for (int mi = 0; mi < 4; ++mi)
                #pragma unroll
                for (int nj = 0; nj < 4; ++nj)
                    acc[mi][nj] = __builtin_amdgcn_mfma_f32_16x16x32_bf16(
                        af[mi], bf[nj], acc[mi][nj], 0, 0, 0);
        }
        __syncthreads();   // all reads done before next DMA lands
    }

    #pragma unroll
    for (int mi = 0; mi < 4; ++mi) {
        #pragma unroll
        for (int nj = 0; nj < 4; ++nj) {
            int gr0 = row0 + mo + mi * 16 + quad * 4;
            int gc  = col0 + no + nj * 16 + lm;
            float bv = bias[gc];
            #pragma unroll
            for (int r = 0; r < 4; ++r) {
                float val = acc[mi][nj][r] + bv;
                int gr = gr0 + r;
                if (out_mode == 0) {
                    ((float*)Cv)[(size_t)gr * 1024 + gc] = val;
                } else if (out_mode == 1) {
                    ((unsigned short*)Cv)[(size_t)gr * 1024 + gc] = f2bf(val);
                } else {
                    int bb = gr >> 10, l = gr & 1023;
                    int hh = gc >> 6,  dd = gc & 63;
                    ((unsigned short*)Cv)[(((size_t)bb * 16 + hh) * 64 + dd) * 1024 + l] = f2bf(val);
                }
            }
        }
    }
}

__global__ __launch_bounds__(256) void qkv_proj(const unsigned short* __restrict__ xb,
                                                const unsigned short* __restrict__ wq,
                                                const unsigned short* __restrict__ wk,
                                                const unsigned short* __restrict__ wv,
                                                const float* __restrict__ bq,
                                                const float* __restrict__ bk,
                                                const float* __restrict__ bv,
                                                unsigned short* __restrict__ Qw,
                                                unsigned short* __restrict__ Kw,
                                                unsigned short* __restrict__ Vt) {
    const int z = blockIdx.z;
    const unsigned short* W = (z == 0) ? wq : (z == 1) ? wk : wv;
    const float* b = (z == 0) ? bq : (z == 1) ? bk : bv;
    void* C = (z == 0) ? (void*)Qw : (z == 1) ? (void*)Kw : (void*)Vt;
    gemm_core(xb, W, b, C, (z == 2) ? 2 : 1);
}

__global__ __launch_bounds__(256) void out_proj(const unsigned short* __restrict__ Aw,
                                                const unsigned short* __restrict__ wo,
                                                const float* __restrict__ bo,
                                                float* __restrict__ out) {
    gemm_core(Aw, wo, bo, out, 0);
}

// ---------------------------------------------------------------------------
// Fused masked attention, per (bh, 128-q tile), 512 threads (8 waves x 16 q).
// Two passes over 8 K-chunks of 128: pass1 online m,l; pass2 recompute,
// normalize, write A fp32 once, P->bf16 via per-wave LDS tile, PV MFMA.
// K/V chunks staged via global_load_lds into unpadded swizzled tiles.
// ---------------------------------------------------------------------------
__global__ __launch_bounds__(512) void attn_fused(const unsigned short* __restrict__ Qw,
                                                  const unsigned short* __restrict__ Kw,
                                                  const unsigned short* __restrict__ Vt,
                                                  const float* __restrict__ bemb,
                                                  float* __restrict__ Aout,
                                                  unsigned short* __restrict__ attn) {
    __shared__ unsigned short Ks[128][64];      // [token][d], swizzled by row&7
    __shared__ unsigned short Vs[64][128];      // [d][token], swizzled by row&15
    __shared__ unsigned short Ps[8][16][132];   // per-wave P tile [qrow][kcol]
    __shared__ float maskadd[1024];
    const int t = threadIdx.x;
    const int lane = t & 63, quad = lane >> 4, lm = lane & 15;
    const int w = t >> 6;                       // wave 0..7
    const int q0 = blockIdx.x * 128;
    const int bh = blockIdx.y;
    const int b = bh >> 4, h = bh & 15;
    const int qrow_frag = q0 + w * 16 + lm;
    const int qrow_acc0 = q0 + w * 16 + quad * 4;
    const int swk = lm & 7;

    // K staging: per wave 2 instrs x 8 rows (1KB); lane row w*16+j*8+(lane>>3)
    const int kr_in = lane >> 3;
    const int ksg = (lane & 7) ^ kr_in;          // (row&7) == kr_in
    const unsigned short* kp = Kw + (size_t)(b * 1024 + w * 16 + kr_in) * 1024 + h * 64 + ksg * 8;
    unsigned short* ldsK = &Ks[w * 16][0];
    // V staging: per wave 2 instrs x 4 rows (1KB); lane row w*8+j*4+(lane>>4)
    const int vr_in = lane >> 4, vcg = lane & 15;
    const int vrow = w * 8 + vr_in;
    const unsigned short* vpbase = Vt + (size_t)bh * 64 * 1024;
    unsigned short* ldsV = &Vs[w * 8][0];

    for (int i = t; i < 1024; i += 512)
        maskadd[i] = (bemb[b * 1024 + i] > 0.f) ? 0.f : -1e30f;

    short8 afq[2];
    #pragma unroll
    for (int s = 0; s < 2; ++s)
        afq[s] = *(const short8*)&Qw[(size_t)(b * 1024 + qrow_frag) * 1024 +
                                     h * 64 + s * 32 + quad * 8];

    float mrun[4], lrun[4];
    #pragma unroll
    for (int r = 0; r < 4; ++r) { mrun[r] = -INFINITY; lrun[r] = 0.f; }

    __syncthreads();   // mask ready

    // ---------------- pass 1: m, l ----------------
    for (int c = 0; c < 8; ++c) {
        #pragma unroll
        for (int j = 0; j < 2; ++j)
            gl2lds16(kp + (size_t)(c * 128 + j * 8) * 1024, ldsK + j * 512);
        __syncthreads();

        f32x4 acc[8] = {};
        #pragma unroll
        for (int s = 0; s < 2; ++s)
            #pragma unroll
            for (int nj = 0; nj < 8; ++nj) {
                short8 bfk = *(const short8*)&Ks[nj * 16 + lm][((s * 4 + quad) ^ swk) * 8];
                acc[nj] = __builtin_amdgcn_mfma_f32_16x16x32_bf16(afq[s], bfk, acc[nj], 0, 0, 0);
            }

        float cmax[4] = { -INFINITY, -INFINITY, -INFINITY, -INFINITY };
        #pragma unroll
        for (int nj = 0; nj < 8; ++nj) {
            float ma = maskadd[c * 128 + nj * 16 + lm];
            #pragma unroll
            for (int r = 0; r < 4; ++r) {
                float sv = acc[nj][r] * 0.125f + ma;
                acc[nj][r] = sv;
                cmax[r] = fmaxf(cmax[r], sv);
            }
        }
        #pragma unroll
        for (int r = 0; r < 4; ++r) {
            #pragma unroll
            for (int off = 8; off >= 1; off >>= 1)
                cmax[r] = fmaxf(cmax[r], __shfl_xor(cmax[r], off, 64));
            float mnew = fmaxf(mrun[r], cmax[r]);
            float csum = 0.f;
            #pragma unroll
            for (int nj = 0; nj < 8; ++nj)
                csum += __expf(acc[nj][r] - mnew);
            #pragma unroll
            for (int off = 8; off >= 1; off >>= 1)
                csum += __shfl_xor(csum, off, 64);
            lrun[r] = lrun[r] * __expf(mrun[r] - mnew) + csum;
            mrun[r] = mnew;
        }
        __syncthreads();   // reads done before next chunk's DMA lands
    }

    float fnorm[4];
    #pragma unroll
    for (int r = 0; r < 4; ++r) {
        bool qp = bemb[b * 1024 + qrow_acc0 + r] > 0.f;
        fnorm[r] = (qp && lrun[r] > 0.f) ? (1.f / lrun[r]) : 0.f;
    }

    // ---------------- pass 2: write A, PV ----------------
    f32x4 oacc[4] = {};
    for (int c = 0; c < 8; ++c) {
        #pragma unroll
        for (int j = 0; j < 2; ++j) {
            gl2lds16(kp + (size_t)(c * 128 + j * 8) * 1024, ldsK + j * 512);
            int rl = vrow + j * 4;
            int vsg = vcg ^ (rl & 15);
            gl2lds16(vpbase + (size_t)rl * 1024 + c * 128 + vsg * 8, ldsV + j * 512);
        }
        __syncthreads();

        f32x4 acc[8] = {};
        #pragma unroll
        for (int s = 0; s < 2; ++s)
            #pragma unroll
            for (int nj = 0; nj < 8; ++nj) {
                short8 bfk = *(const short8*)&Ks[nj * 16 + lm][((s * 4 + quad) ^ swk) * 8];
                acc[nj] = __builtin_amdgcn_mfma_f32_16x16x32_bf16(afq[s], bfk, acc[nj], 0, 0, 0);
            }

        #pragma unroll
        for (int nj = 0; nj < 8; ++nj) {
            float ma = maskadd[c * 128 + nj * 16 + lm];
            #pragma unroll
            for (int r = 0; r < 4; ++r) {
                float sv = acc[nj][r] * 0.125f + ma;
                float p  = __expf(sv - mrun[r]);
                float a  = p * fnorm[r];
                Aout[((size_t)bh * 1024 + qrow_acc0 + r) * 1024 + c * 128 + nj * 16 + lm] = a;
                Ps[w][quad * 4 + r][nj * 16 + lm] = f2bf(a);
            }
        }

        // PV (wave-local LDS round-trip; in-wave lgkmcnt ordering is safe)
        #pragma unroll
        for (int ks = 0; ks < 4; ++ks) {
            short8 afp = *(const short8*)&Ps[w][lm][ks * 32 + quad * 8];
            #pragma unroll
            for (int nd = 0; nd < 4; ++nd) {
                short8 bfv = *(const short8*)&Vs[nd * 16 + lm][((ks * 4 + quad) ^ lm) * 8];
                oacc[nd] = __builtin_amdgcn_mfma_f32_16x16x32_bf16(afp, bfv, oacc[nd], 0, 0, 0);
            }
        }
        __syncthreads();
    }

    #pragma unroll
    for (int nd = 0; nd < 4; ++nd)
        #pragma unroll
        for (int r = 0; r < 4; ++r)
            attn[(size_t)(b * 1024 + qrow_acc0 + r) * 1024 + h * 64 + nd * 16 + lm] =
                f2bf(oacc[nd][r]);
}

// ---------------------------------------------------------------------------
extern "C" void kernel_launch(void* const* d_in, const int* in_sizes, int n_in,
                              void* d_out, int out_size, void* d_ws, size_t ws_size,
                              hipStream_t stream) {
    const float* x    = (const float*)d_in[0];
    const float* bemb = (const float*)d_in[1];
    const float* Wq   = (const float*)d_in[2];
    const float* Wq_b = (const float*)d_in[3];
    const float* Wk   = (const float*)d_in[4];
    const float* Wk_b = (const float*)d_in[5];
    const float* Wv   = (const float*)d_in[6];
    const float* Wv_b = (const float*)d_in[7];
    const float* Wo   = (const float*)d_in[8];
    const float* Wo_b = (const float*)d_in[9];

    float* out  = (float*)d_out;                      // [B,L,D] fp32
    float* Aout = out + (size_t)BB * LL * DD;         // [B,H,L,L] fp32

    unsigned short* x_bf  = (unsigned short*)d_ws;              // 4M u16 (reused as Aw)
    unsigned short* Wq_bf = x_bf  + (size_t)MROWS * DD;
    unsigned short* Wk_bf = Wq_bf + (size_t)DD * DD;
    unsigned short* Wv_bf = Wk_bf + (size_t)DD * DD;
    unsigned short* Wo_bf = Wv_bf + (size_t)DD * DD;
    unsigned short* Qw    = Wo_bf + (size_t)DD * DD;
    unsigned short* Kw    = Qw + (size_t)MROWS * DD;
    unsigned short* Vt    = Kw + (size_t)MROWS * DD;
    unsigned short* Aw    = x_bf;   // x_bf dead after projections

    cvt_all<<<dim3(8192), dim3(256), 0, stream>>>(x, Wq, Wk, Wv, Wo,
                                                  x_bf, Wq_bf, Wk_bf, Wv_bf, Wo_bf);

    qkv_proj<<<dim3(MROWS / 128, DD / 128, 3), dim3(256), 0, stream>>>(
        x_bf, Wq_bf, Wk_bf, Wv_bf, Wq_b, Wk_b, Wv_b, Qw, Kw, Vt);

    attn_fused<<<dim3(LL / 128, BB * HH), dim3(512), 0, stream>>>(
        Qw, Kw, Vt, bemb, Aout, Aw);

    out_proj<<<dim3(MROWS / 128, DD / 128), dim3(256), 0, stream>>>(
        Aw, Wo_bf, Wo_b, out);
}